// Round 1
// baseline (360.427 us; speedup 1.0000x reference)
//
#include <hip/hip_runtime.h>

#define N_TOT 8192
#define BHALF 4096
#define D_DIM 512
#define LDA 520   // 512 + 8 bf16 pad: keeps 16B alignment, spreads banks

typedef float f32x4 __attribute__((ext_vector_type(4)));
typedef short s16x8 __attribute__((ext_vector_type(8)));  // 8 bf16 in 4 VGPRs

__device__ __forceinline__ unsigned short f2bf(float x) {
    union { float f; unsigned int u; } v; v.f = x;
    unsigned int lsb = (v.u >> 16) & 1u;
    unsigned int r = v.u + 0x7fffu + lsb;   // round-to-nearest-even
    return (unsigned short)(r >> 16);
}

// Kernel 1: row L2-normalize [zjs; zis] -> bf16 Z in workspace.
__global__ __launch_bounds__(256) void normalize_kernel(
    const float* __restrict__ zis, const float* __restrict__ zjs,
    unsigned short* __restrict__ zb)
{
    int wave = threadIdx.x >> 6;
    int lane = threadIdx.x & 63;
    int row  = blockIdx.x * 4 + wave;
    const float* src = (row < BHALF) ? (zjs + (size_t)row * D_DIM)
                                     : (zis + (size_t)(row - BHALF) * D_DIM);
    const float4* src4 = (const float4*)src;
    float4 v0 = src4[lane * 2];
    float4 v1 = src4[lane * 2 + 1];
    float ss = v0.x*v0.x + v0.y*v0.y + v0.z*v0.z + v0.w*v0.w
             + v1.x*v1.x + v1.y*v1.y + v1.z*v1.z + v1.w*v1.w;
    #pragma unroll
    for (int off = 1; off < 64; off <<= 1) ss += __shfl_xor(ss, off);
    float scale = 1.0f / fmaxf(sqrtf(ss), 1e-8f);

    float vals[8] = {v0.x, v0.y, v0.z, v0.w, v1.x, v1.y, v1.z, v1.w};
    unsigned short u[8];
    #pragma unroll
    for (int i = 0; i < 8; ++i) u[i] = f2bf(vals[i] * scale);
    uint4 o;
    o.x = u[0] | ((unsigned)u[1] << 16);
    o.y = u[2] | ((unsigned)u[3] << 16);
    o.z = u[4] | ((unsigned)u[5] << 16);
    o.w = u[6] | ((unsigned)u[7] << 16);
    ((uint4*)(zb + (size_t)row * D_DIM))[lane] = o;
}

// Kernel 2: fused Z·Z^T / TEMP -> exp -> row-sum (diag masked), pos extract,
// per-row log(sum)-pos, block-sum, atomicAdd of mean contribution.
__global__ __launch_bounds__(512, 2) void ntxent_kernel(
    const unsigned short* __restrict__ zb, float* __restrict__ out)
{
    __shared__ unsigned short As[32 * LDA];   // 33280 B
    __shared__ float rs_lds[32];
    __shared__ float pos_lds[32];

    const int tid  = threadIdx.x;
    const int wave = tid >> 6;
    const int lane = tid & 63;
    const int rowbase = blockIdx.x * 32;

    // Stage A: 32 rows x 512 bf16, padded stride LDA. Coalesced 16B copies.
    for (int i = tid; i < 32 * (D_DIM / 8); i += 512) {
        int r = i >> 6;     // 64 chunks of 8 bf16 per row
        int c = i & 63;
        *(uint4*)&As[r * LDA + c * 8] =
            *(const uint4*)&zb[(size_t)(rowbase + r) * D_DIM + c * 8];
    }
    if (tid < 32) rs_lds[tid] = 0.0f;
    __syncthreads();

    const int cq   = lane & 15;   // col-in-tile (B) / row-in-tile (A)
    const int quad = lane >> 4;

    float esum[8] = {0.f,0.f,0.f,0.f,0.f,0.f,0.f,0.f};

    for (int ct = 0; ct < N_TOT / 128; ++ct) {
        const int colbase = ct * 128 + wave * 16;
        f32x4 acc0 = {0.f, 0.f, 0.f, 0.f};
        f32x4 acc1 = {0.f, 0.f, 0.f, 0.f};
        const unsigned short* bptr  = zb + (size_t)(colbase + cq) * D_DIM + quad * 8;
        const unsigned short* aptr0 = &As[cq * LDA + quad * 8];
        const unsigned short* aptr1 = &As[(cq + 16) * LDA + quad * 8];
        #pragma unroll
        for (int ks = 0; ks < 16; ++ks) {
            s16x8 b  = *(const s16x8*)(bptr  + ks * 32);
            s16x8 a0 = *(const s16x8*)(aptr0 + ks * 32);
            s16x8 a1 = *(const s16x8*)(aptr1 + ks * 32);
            acc0 = __builtin_amdgcn_mfma_f32_16x16x32_bf16(a0, b, acc0, 0, 0, 0);
            acc1 = __builtin_amdgcn_mfma_f32_16x16x32_bf16(a1, b, acc1, 0, 0, 0);
        }
        const int gc = colbase + cq;
        #pragma unroll
        for (int rt = 0; rt < 2; ++rt) {
            f32x4 acc = rt ? acc1 : acc0;
            #pragma unroll
            for (int reg = 0; reg < 4; ++reg) {
                int lr = rt * 16 + quad * 4 + reg;     // C/D: row = quad*4+reg
                int gr = rowbase + lr;
                float sim = acc[reg] * 2.0f;           // /TEMP
                if (gc == gr) continue;                // mask diagonal
                esum[rt * 4 + reg] += __expf(sim);
                if (gc == ((gr + BHALF) & (N_TOT - 1))) pos_lds[lr] = sim;
            }
        }
    }

    // Reduce esum across the 16 column-lanes (same row within a quad-group).
    #pragma unroll
    for (int j = 0; j < 8; ++j) {
        float v = esum[j];
        v += __shfl_xor(v, 1); v += __shfl_xor(v, 2);
        v += __shfl_xor(v, 4); v += __shfl_xor(v, 8);
        esum[j] = v;
    }
    if (cq == 0) {
        #pragma unroll
        for (int rt = 0; rt < 2; ++rt)
            #pragma unroll
            for (int reg = 0; reg < 4; ++reg)
                atomicAdd(&rs_lds[rt * 16 + quad * 4 + reg], esum[rt * 4 + reg]);
    }
    __syncthreads();

    if (tid < 32) {
        float per = __logf(rs_lds[tid]) - pos_lds[tid];
        per += __shfl_xor(per, 1); per += __shfl_xor(per, 2);
        per += __shfl_xor(per, 4); per += __shfl_xor(per, 8);
        per += __shfl_xor(per, 16);
        if (tid == 0) atomicAdd(out, per * (1.0f / N_TOT));
    }
}

extern "C" void kernel_launch(void* const* d_in, const int* in_sizes, int n_in,
                              void* d_out, int out_size, void* d_ws, size_t ws_size,
                              hipStream_t stream) {
    const float* zis = (const float*)d_in[0];
    const float* zjs = (const float*)d_in[1];
    unsigned short* zb = (unsigned short*)d_ws;   // 8192*512 bf16 = 8 MB
    float* out = (float*)d_out;

    hipMemsetAsync(d_out, 0, sizeof(float), stream);
    normalize_kernel<<<N_TOT / 4, 256, 0, stream>>>(zis, zjs, zb);
    ntxent_kernel<<<N_TOT / 32, 512, 0, stream>>>(zb, out);
}

// Round 2
// 158.083 us; speedup vs baseline: 2.2800x; 2.2800x over previous
//
#include <hip/hip_runtime.h>

#define N_TOT 8192
#define BHALF 4096
#define D_DIM 512
#define BM 128
#define BK 64
#define NTILE 64          // N_TOT / BM
#define NBLOCKS 2080      // NTILE*(NTILE+1)/2 upper-triangle tiles

typedef float f32x4 __attribute__((ext_vector_type(4)));
typedef short s16x8 __attribute__((ext_vector_type(8)));  // 8 bf16 in 4 VGPRs

__device__ __forceinline__ unsigned short f2bf(float x) {
    union { float f; unsigned int u; } v; v.f = x;
    unsigned int lsb = (v.u >> 16) & 1u;
    unsigned int r = v.u + 0x7fffu + lsb;   // round-to-nearest-even
    return (unsigned short)(r >> 16);
}

// Kernel 1: row L2-normalize [zjs; zis] -> bf16 Z in workspace.
__global__ __launch_bounds__(256) void normalize_kernel(
    const float* __restrict__ zis, const float* __restrict__ zjs,
    unsigned short* __restrict__ zb)
{
    int wave = threadIdx.x >> 6;
    int lane = threadIdx.x & 63;
    int row  = blockIdx.x * 4 + wave;
    const float* src = (row < BHALF) ? (zjs + (size_t)row * D_DIM)
                                     : (zis + (size_t)(row - BHALF) * D_DIM);
    const float4* src4 = (const float4*)src;
    float4 v0 = src4[lane * 2];
    float4 v1 = src4[lane * 2 + 1];
    float ss = v0.x*v0.x + v0.y*v0.y + v0.z*v0.z + v0.w*v0.w
             + v1.x*v1.x + v1.y*v1.y + v1.z*v1.z + v1.w*v1.w;
    #pragma unroll
    for (int off = 1; off < 64; off <<= 1) ss += __shfl_xor(ss, off);
    float scale = 1.0f / fmaxf(sqrtf(ss), 1e-8f);

    float vals[8] = {v0.x, v0.y, v0.z, v0.w, v1.x, v1.y, v1.z, v1.w};
    unsigned short u[8];
    #pragma unroll
    for (int i = 0; i < 8; ++i) u[i] = f2bf(vals[i] * scale);
    uint4 o;
    o.x = u[0] | ((unsigned)u[1] << 16);
    o.y = u[2] | ((unsigned)u[3] << 16);
    o.z = u[4] | ((unsigned)u[5] << 16);
    o.w = u[6] | ((unsigned)u[7] << 16);
    ((uint4*)(zb + (size_t)row * D_DIM))[lane] = o;
}

// Kernel 2: upper-triangle 128x128 tiles of exp(2*Z.Z^T), diag masked.
// Row-sums accumulated to global rowsum[] (col-side too, via symmetry).
__global__ __launch_bounds__(256) void ntxent_tri_kernel(
    const unsigned short* __restrict__ zb, float* __restrict__ rowsum)
{
    // XOR-swizzled: 16B unit for (row r, k-chunk c8) lives at unit r*8 + (c8^(r&7))
    __shared__ unsigned short As[BM * BK];   // 16 KB
    __shared__ unsigned short Bs[BM * BK];   // 16 KB
    __shared__ float rsum_lds[BM];
    __shared__ float csum_lds[BM];

    const int tid  = threadIdx.x;
    const int wave = tid >> 6;
    const int lane = tid & 63;
    const int cq   = lane & 15;
    const int quad = lane >> 4;
    const int wr   = wave >> 1;    // wave row 0..1
    const int wc   = wave & 1;     // wave col 0..1

    // blockIdx -> (I,J) with I<=J (block-uniform scalar loop)
    int I = 0, rem = blockIdx.x;
    while (rem >= NTILE - I) { rem -= NTILE - I; ++I; }
    const int J = I + rem;
    const int rowbase = I * BM;
    const int colbase = J * BM;
    const bool diagblk = (I == J);

    if (tid < BM) { rsum_lds[tid] = 0.0f; csum_lds[tid] = 0.0f; }

    f32x4 acc[4][4];
    #pragma unroll
    for (int a = 0; a < 4; ++a)
        #pragma unroll
        for (int b = 0; b < 4; ++b)
            acc[a][b] = (f32x4){0.f, 0.f, 0.f, 0.f};

    for (int kc = 0; kc < D_DIM; kc += BK) {
        __syncthreads();   // previous chunk's readers done (also covers lds zero-init)
        #pragma unroll
        for (int rnd = 0; rnd < 4; ++rnd) {
            int s  = rnd * 256 + tid;        // 16B unit index, 0..1023
            int r  = s >> 3;                 // local row 0..127
            int c8 = (s & 7) ^ (r & 7);      // swizzled global k-chunk
            const unsigned short* ga = zb + (size_t)(rowbase + r) * D_DIM + kc + c8 * 8;
            const unsigned short* gb = zb + (size_t)(colbase + r) * D_DIM + kc + c8 * 8;
            __builtin_amdgcn_global_load_lds(
                (const __attribute__((address_space(1))) unsigned int*)ga,
                (__attribute__((address_space(3))) unsigned int*)&As[s * 8], 16, 0, 0);
            __builtin_amdgcn_global_load_lds(
                (const __attribute__((address_space(1))) unsigned int*)gb,
                (__attribute__((address_space(3))) unsigned int*)&Bs[s * 8], 16, 0, 0);
        }
        __syncthreads();   // staging complete

        #pragma unroll
        for (int kk = 0; kk < 2; ++kk) {     // two k-steps of 32 per chunk
            s16x8 af[4], bf[4];
            const int c8a = kk * 4 + quad;   // global k-chunk for this fragment
            #pragma unroll
            for (int t = 0; t < 4; ++t) {
                int ra = wr * 64 + t * 16 + cq;
                int rb = wc * 64 + t * 16 + cq;
                af[t] = *(const s16x8*)&As[(ra * 8 + (c8a ^ (ra & 7))) * 8];
                bf[t] = *(const s16x8*)&Bs[(rb * 8 + (c8a ^ (rb & 7))) * 8];
            }
            #pragma unroll
            for (int ar = 0; ar < 4; ++ar)
                #pragma unroll
                for (int bc = 0; bc < 4; ++bc)
                    acc[ar][bc] = __builtin_amdgcn_mfma_f32_16x16x32_bf16(
                        af[ar], bf[bc], acc[ar][bc], 0, 0, 0);
        }
    }

    // Epilogue: exp (diag masked) in-place, then row/col reductions.
    #pragma unroll
    for (int ar = 0; ar < 4; ++ar)
        #pragma unroll
        for (int bc = 0; bc < 4; ++bc)
            #pragma unroll
            for (int reg = 0; reg < 4; ++reg) {
                int gr = rowbase + wr * 64 + ar * 16 + quad * 4 + reg;
                int gc = colbase + wc * 64 + bc * 16 + cq;
                float e = __expf(acc[ar][bc][reg] * 2.0f);   // /TEMP
                acc[ar][bc][reg] = (gr == gc) ? 0.0f : e;
            }

    // Row sums: sum over 16 cols (bc in-register, cq via shuffle).
    #pragma unroll
    for (int ar = 0; ar < 4; ++ar) {
        float rs[4];
        #pragma unroll
        for (int reg = 0; reg < 4; ++reg) {
            float v = acc[ar][0][reg] + acc[ar][1][reg] + acc[ar][2][reg] + acc[ar][3][reg];
            v += __shfl_xor(v, 1); v += __shfl_xor(v, 2);
            v += __shfl_xor(v, 4); v += __shfl_xor(v, 8);
            rs[reg] = v;
        }
        if (cq == 0) {
            #pragma unroll
            for (int reg = 0; reg < 4; ++reg)
                atomicAdd(&rsum_lds[wr * 64 + ar * 16 + quad * 4 + reg], rs[reg]);
        }
    }

    // Col sums (symmetry): only for off-diagonal blocks.
    if (!diagblk) {
        #pragma unroll
        for (int bc = 0; bc < 4; ++bc) {
            float cs = 0.0f;
            #pragma unroll
            for (int ar = 0; ar < 4; ++ar)
                #pragma unroll
                for (int reg = 0; reg < 4; ++reg)
                    cs += acc[ar][bc][reg];
            cs += __shfl_xor(cs, 16); cs += __shfl_xor(cs, 32);
            if (quad == 0) atomicAdd(&csum_lds[wc * 64 + bc * 16 + cq], cs);
        }
    }

    __syncthreads();
    if (tid < BM) atomicAdd(&rowsum[rowbase + tid], rsum_lds[tid]);
    else if (!diagblk) atomicAdd(&rowsum[colbase + tid - BM], csum_lds[tid - BM]);
}

// Kernel 3: per-row log(rowsum) - pos, mean-reduce into out.
__global__ __launch_bounds__(256) void finalize_kernel(
    const unsigned short* __restrict__ zb, const float* __restrict__ rowsum,
    float* __restrict__ out)
{
    __shared__ float acc_lds[4];
    int wave = threadIdx.x >> 6;
    int lane = threadIdx.x & 63;
    int row  = blockIdx.x * 4 + wave;
    int pair = (row + BHALF) & (N_TOT - 1);
    const uint4* ap = (const uint4*)(zb + (size_t)row * D_DIM);
    const uint4* bp = (const uint4*)(zb + (size_t)pair * D_DIM);
    uint4 a = ap[lane], b = bp[lane];
    float dot = 0.0f;
    unsigned ax[4] = {a.x, a.y, a.z, a.w};
    unsigned bx[4] = {b.x, b.y, b.z, b.w};
    #pragma unroll
    for (int i = 0; i < 4; ++i) {
        float xl = __uint_as_float(ax[i] << 16);
        float yl = __uint_as_float(bx[i] << 16);
        float xh = __uint_as_float(ax[i] & 0xffff0000u);
        float yh = __uint_as_float(bx[i] & 0xffff0000u);
        dot += xl * yl + xh * yh;
    }
    #pragma unroll
    for (int off = 1; off < 64; off <<= 1) dot += __shfl_xor(dot, off);
    if (lane == 0) acc_lds[wave] = __logf(rowsum[row]) - dot * 2.0f;
    __syncthreads();
    if (threadIdx.x == 0) {
        float s = acc_lds[0] + acc_lds[1] + acc_lds[2] + acc_lds[3];
        atomicAdd(out, s * (1.0f / N_TOT));
    }
}

extern "C" void kernel_launch(void* const* d_in, const int* in_sizes, int n_in,
                              void* d_out, int out_size, void* d_ws, size_t ws_size,
                              hipStream_t stream) {
    const float* zis = (const float*)d_in[0];
    const float* zjs = (const float*)d_in[1];
    float* rowsum = (float*)d_ws;                                   // 32 KB
    unsigned short* zb = (unsigned short*)((float*)d_ws + N_TOT);   // 8 MB
    float* out = (float*)d_out;

    hipMemsetAsync(d_out, 0, sizeof(float), stream);
    hipMemsetAsync(rowsum, 0, N_TOT * sizeof(float), stream);
    normalize_kernel<<<N_TOT / 4, 256, 0, stream>>>(zis, zjs, zb);
    ntxent_tri_kernel<<<NBLOCKS, 256, 0, stream>>>(zb, rowsum);
    finalize_kernel<<<N_TOT / 4, 256, 0, stream>>>(zb, rowsum, out);
}

// Round 3
// 133.496 us; speedup vs baseline: 2.6999x; 1.1842x over previous
//
#include <hip/hip_runtime.h>

#define N_TOT 8192
#define BHALF 4096
#define D_DIM 512
#define BM 128
#define BK 64
#define NTILE 64          // N_TOT / BM
#define NBLOCKS 2080      // NTILE*(NTILE+1)/2 upper-triangle tiles

typedef float f32x4 __attribute__((ext_vector_type(4)));
typedef short s16x8 __attribute__((ext_vector_type(8)));  // 8 bf16 in 4 VGPRs

__device__ __forceinline__ unsigned short f2bf(float x) {
    union { float f; unsigned int u; } v; v.f = x;
    unsigned int lsb = (v.u >> 16) & 1u;
    unsigned int r = v.u + 0x7fffu + lsb;   // round-to-nearest-even
    return (unsigned short)(r >> 16);
}

// Kernel 1: row L2-normalize [zjs; zis] -> bf16 Z; blocks 0..31 zero rowsum.
__global__ __launch_bounds__(256) void normalize_kernel(
    const float* __restrict__ zis, const float* __restrict__ zjs,
    unsigned short* __restrict__ zb, float* __restrict__ rowsum)
{
    if (blockIdx.x < 32) rowsum[blockIdx.x * 256 + threadIdx.x] = 0.0f;
    int wave = threadIdx.x >> 6;
    int lane = threadIdx.x & 63;
    int row  = blockIdx.x * 4 + wave;
    const float* src = (row < BHALF) ? (zjs + (size_t)row * D_DIM)
                                     : (zis + (size_t)(row - BHALF) * D_DIM);
    const float4* src4 = (const float4*)src;
    float4 v0 = src4[lane * 2];
    float4 v1 = src4[lane * 2 + 1];
    float ss = v0.x*v0.x + v0.y*v0.y + v0.z*v0.z + v0.w*v0.w
             + v1.x*v1.x + v1.y*v1.y + v1.z*v1.z + v1.w*v1.w;
    #pragma unroll
    for (int off = 1; off < 64; off <<= 1) ss += __shfl_xor(ss, off);
    float scale = 1.0f / fmaxf(sqrtf(ss), 1e-8f);

    float vals[8] = {v0.x, v0.y, v0.z, v0.w, v1.x, v1.y, v1.z, v1.w};
    unsigned short u[8];
    #pragma unroll
    for (int i = 0; i < 8; ++i) u[i] = f2bf(vals[i] * scale);
    uint4 o;
    o.x = u[0] | ((unsigned)u[1] << 16);
    o.y = u[2] | ((unsigned)u[3] << 16);
    o.z = u[4] | ((unsigned)u[5] << 16);
    o.w = u[6] | ((unsigned)u[7] << 16);
    ((uint4*)(zb + (size_t)row * D_DIM))[lane] = o;
}

// Kernel 2: upper-triangle 128x128 tiles of exp(2*Z.Z^T), diag masked.
// Row/col sums -> rowsum[] via symmetry; pos sims extracted on J==I+32 tiles.
__global__ __launch_bounds__(256) void ntxent_tri_kernel(
    const unsigned short* __restrict__ zb, float* __restrict__ rowsum,
    float* __restrict__ pos_ws)
{
    // XOR-swizzled: 16B unit for (row r, k-chunk c8) lives at unit r*8 + (c8^(r&7))
    __shared__ unsigned short As[BM * BK];   // 16 KB
    __shared__ unsigned short Bs[BM * BK];   // 16 KB
    __shared__ float rsum_lds[BM];
    __shared__ float csum_lds[BM];

    const int tid  = threadIdx.x;
    const int wave = tid >> 6;
    const int lane = tid & 63;
    const int cq   = lane & 15;
    const int quad = lane >> 4;
    const int wr   = wave >> 1;    // wave row 0..1
    const int wc   = wave & 1;     // wave col 0..1

    // blockIdx -> (I,J), J-group-major (8 J-panels/group), I-major in group.
    // Group g holds 64g+36 tiles; B working set/group = 8*128 rows = 1 MB (L2-hot).
    int g = 0, rem = blockIdx.x;
    while (rem >= 64 * g + 36) { rem -= 64 * g + 36; ++g; }
    int I, J;
    if (rem < 64 * g) { I = rem >> 3; J = 8 * g + (rem & 7); }
    else {
        rem -= 64 * g;
        int ii = 0;
        while (rem >= 8 - ii) { rem -= 8 - ii; ++ii; }
        I = 8 * g + ii;
        J = I + rem;
    }
    const int rowbase = I * BM;
    const int colbase = J * BM;
    const bool diagblk = (I == J);
    const bool posblk  = (J == I + NTILE / 2);   // contains (i, i+BHALF) pairs

    if (tid < BM) { rsum_lds[tid] = 0.0f; csum_lds[tid] = 0.0f; }

    // Hoisted staging addresses: swizzled k-chunk is invariant (rnd*32 % 8 == 0).
    const int r0  = tid >> 3;                       // 0..31
    const int c8s = (tid & 7) ^ (r0 & 7);
    const unsigned short* gA[4];
    const unsigned short* gB[4];
    #pragma unroll
    for (int rnd = 0; rnd < 4; ++rnd) {
        int r = rnd * 32 + r0;
        gA[rnd] = zb + (size_t)(rowbase + r) * D_DIM + c8s * 8;
        gB[rnd] = zb + (size_t)(colbase + r) * D_DIM + c8s * 8;
    }

    // Hoisted fragment-read constants.
    int aOff[4], aSw[4], bOff[4], bSw[4];
    #pragma unroll
    for (int t = 0; t < 4; ++t) {
        int ra = wr * 64 + t * 16 + cq;
        int rb = wc * 64 + t * 16 + cq;
        aOff[t] = ra * 64; aSw[t] = ra & 7;
        bOff[t] = rb * 64; bSw[t] = rb & 7;
    }

    f32x4 acc[4][4];
    #pragma unroll
    for (int a = 0; a < 4; ++a)
        #pragma unroll
        for (int b = 0; b < 4; ++b)
            acc[a][b] = (f32x4){0.f, 0.f, 0.f, 0.f};

    for (int kc = 0; kc < D_DIM / BK; ++kc) {
        __syncthreads();   // previous chunk's readers done (covers lds init)
        #pragma unroll
        for (int rnd = 0; rnd < 4; ++rnd) {
            __builtin_amdgcn_global_load_lds(
                (const __attribute__((address_space(1))) unsigned int*)gA[rnd],
                (__attribute__((address_space(3))) unsigned int*)&As[(rnd * 256 + tid) * 8],
                16, 0, 0);
            __builtin_amdgcn_global_load_lds(
                (const __attribute__((address_space(1))) unsigned int*)gB[rnd],
                (__attribute__((address_space(3))) unsigned int*)&Bs[(rnd * 256 + tid) * 8],
                16, 0, 0);
            gA[rnd] += BK; gB[rnd] += BK;
        }
        __syncthreads();   // staging complete

        #pragma unroll
        for (int kk = 0; kk < 2; ++kk) {     // two k-steps of 32 per chunk
            s16x8 af[4], bf[4];
            const int c8a = kk * 4 + quad;
            #pragma unroll
            for (int t = 0; t < 4; ++t) {
                af[t] = *(const s16x8*)&As[aOff[t] + ((c8a ^ aSw[t]) << 3)];
                bf[t] = *(const s16x8*)&Bs[bOff[t] + ((c8a ^ bSw[t]) << 3)];
            }
            #pragma unroll
            for (int ar = 0; ar < 4; ++ar)
                #pragma unroll
                for (int bc = 0; bc < 4; ++bc)
                    acc[ar][bc] = __builtin_amdgcn_mfma_f32_16x16x32_bf16(
                        af[ar], bf[bc], acc[ar][bc], 0, 0, 0);
        }
    }

    // pos extraction BEFORE exp: gc == gr + BHALF  <=>  wc==wr, bc==ar, cq==quad*4+reg
    if (posblk && wc == wr) {
        #pragma unroll
        for (int ar = 0; ar < 4; ++ar)
            #pragma unroll
            for (int reg = 0; reg < 4; ++reg)
                if (cq == quad * 4 + reg) {
                    int gr = rowbase + wr * 64 + ar * 16 + quad * 4 + reg;
                    pos_ws[gr] = acc[ar][ar][reg] * 2.0f;   // sim value; gr < BHALF
                }
    }

    // exp (diag mask only on diagonal blocks)
    #pragma unroll
    for (int ar = 0; ar < 4; ++ar)
        #pragma unroll
        for (int bc = 0; bc < 4; ++bc)
            #pragma unroll
            for (int reg = 0; reg < 4; ++reg)
                acc[ar][bc][reg] = __expf(acc[ar][bc][reg] * 2.0f);
    if (diagblk && wr == wc) {
        #pragma unroll
        for (int ar = 0; ar < 4; ++ar)
            #pragma unroll
            for (int reg = 0; reg < 4; ++reg)
                if (cq == quad * 4 + reg) acc[ar][ar][reg] = 0.0f;
    }

    // Row sums: sum over 16 cols (bc in-register, cq via shuffle).
    #pragma unroll
    for (int ar = 0; ar < 4; ++ar) {
        float rs[4];
        #pragma unroll
        for (int reg = 0; reg < 4; ++reg) {
            float v = acc[ar][0][reg] + acc[ar][1][reg] + acc[ar][2][reg] + acc[ar][3][reg];
            v += __shfl_xor(v, 1); v += __shfl_xor(v, 2);
            v += __shfl_xor(v, 4); v += __shfl_xor(v, 8);
            rs[reg] = v;
        }
        if (cq == 0) {
            #pragma unroll
            for (int reg = 0; reg < 4; ++reg)
                atomicAdd(&rsum_lds[wr * 64 + ar * 16 + quad * 4 + reg], rs[reg]);
        }
    }

    // Col sums (symmetry): only for off-diagonal blocks.
    if (!diagblk) {
        #pragma unroll
        for (int bc = 0; bc < 4; ++bc) {
            float cs = 0.0f;
            #pragma unroll
            for (int ar = 0; ar < 4; ++ar)
                #pragma unroll
                for (int reg = 0; reg < 4; ++reg)
                    cs += acc[ar][bc][reg];
            cs += __shfl_xor(cs, 16); cs += __shfl_xor(cs, 32);
            if (quad == 0) atomicAdd(&csum_lds[wc * 64 + bc * 16 + cq], cs);
        }
    }

    __syncthreads();
    if (tid < BM) atomicAdd(&rowsum[rowbase + tid], rsum_lds[tid]);
    else if (!diagblk) atomicAdd(&rowsum[colbase + tid - BM], csum_lds[tid - BM]);
}

// Kernel 3: single block. mean_r( log(rowsum[r]) - pos[r & (BHALF-1)] ).
__global__ __launch_bounds__(256) void finalize_kernel(
    const float* __restrict__ rowsum, const float* __restrict__ pos_ws,
    float* __restrict__ out)
{
    __shared__ float red[4];
    float s = 0.0f;
    for (int r = threadIdx.x; r < N_TOT; r += 256)
        s += __logf(rowsum[r]) - pos_ws[r & (BHALF - 1)];
    #pragma unroll
    for (int off = 1; off < 64; off <<= 1) s += __shfl_xor(s, off);
    int wave = threadIdx.x >> 6, lane = threadIdx.x & 63;
    if (lane == 0) red[wave] = s;
    __syncthreads();
    if (threadIdx.x == 0)
        out[0] = (red[0] + red[1] + red[2] + red[3]) * (1.0f / N_TOT);
}

extern "C" void kernel_launch(void* const* d_in, const int* in_sizes, int n_in,
                              void* d_out, int out_size, void* d_ws, size_t ws_size,
                              hipStream_t stream) {
    const float* zis = (const float*)d_in[0];
    const float* zjs = (const float*)d_in[1];
    float* rowsum = (float*)d_ws;                                   // 32 KB
    float* pos_ws = (float*)d_ws + N_TOT;                           // 16 KB
    unsigned short* zb = (unsigned short*)((float*)d_ws + N_TOT + BHALF);  // 8 MB
    float* out = (float*)d_out;

    normalize_kernel<<<N_TOT / 4, 256, 0, stream>>>(zis, zjs, zb, rowsum);
    ntxent_tri_kernel<<<NBLOCKS, 256, 0, stream>>>(zb, rowsum, pos_ws);
    finalize_kernel<<<1, 256, 0, stream>>>(rowsum, pos_ws, out);
}